// Round 13
// baseline (454.065 us; speedup 1.0000x reference)
//
#include <hip/hip_runtime.h>
#include <math.h>

#define Bn 8192
#define Sn 200
#define Fn 128
#define En 64
#define An 64
#define H1n 128
#define H2n 64
#define H3n 32
#define EPSn 1e-5f

typedef __attribute__((ext_vector_type(8))) short bf16x8;
typedef __attribute__((ext_vector_type(4))) float f32x4;

__device__ __forceinline__ uint pack_bf2(float a, float b) {
    uint ua = __float_as_uint(a), ub = __float_as_uint(b);
    ua += 0x7fffu + ((ua >> 16) & 1u);
    ub += 0x7fffu + ((ub >> 16) & 1u);
    return (ua >> 16) | (ub & 0xffff0000u);
}
__device__ __forceinline__ ushort bf16_1(float a) {
    uint u = __float_as_uint(a);
    u += 0x7fffu + ((u >> 16) & 1u);
    return (ushort)(u >> 16);
}

__device__ __forceinline__ void pack_frag(const float* __restrict__ src,
                                          ushort* __restrict__ dst,
                                          int p, int N, int nk) {
    int j = p & 7, l = (p >> 3) & 63, t = p >> 9;
    int k = t % nk, ct = t / nk;
    int row = k * 32 + 8 * (l >> 4) + j;
    int col = ct * 16 + (l & 15);
    dst[p] = bf16_1(src[row * N + col]);
}

// ---------- K1: all weight prep in ONE kernel (201 blocks) ----------
__global__ void k_prep(
    const float* __restrict__ Wi, const float* __restrict__ bi,
    const float* __restrict__ Wk, const float* __restrict__ Wq,
    const float* __restrict__ W1, const float* __restrict__ W2,
    const float* __restrict__ W3,
    const float* __restrict__ b1, const float* __restrict__ g1,
    const float* __restrict__ be1, const float* __restrict__ m1,
    const float* __restrict__ v1,
    const float* __restrict__ b2, const float* __restrict__ g2,
    const float* __restrict__ be2, const float* __restrict__ m2,
    const float* __restrict__ v2,
    const float* __restrict__ b3, const float* __restrict__ g3,
    const float* __restrict__ be3, const float* __restrict__ m3,
    const float* __restrict__ v3,
    ushort* __restrict__ wikp, ushort* __restrict__ wiqp, float* __restrict__ bq,
    ushort* __restrict__ wip, ushort* __restrict__ w1p,
    ushort* __restrict__ w2p, ushort* __restrict__ w3p,
    float* __restrict__ al1, float* __restrict__ bt1,
    float* __restrict__ al2, float* __restrict__ bt2,
    float* __restrict__ al3, float* __restrict__ bt3) {
    const int blk = blockIdx.x, tid = threadIdx.x;
    if (blk < 32) {
        int idx = blk * 256 + tid;
        int j = idx & 7, l = (idx >> 3) & 63, t = idx >> 9;
        int k = t & 3, ct = t >> 2;
        int row = k * 32 + 8 * (l >> 4) + j;
        int col = ct * 16 + (l & 15);
        float sk = 0.f, sq = 0.f;
        for (int e = 0; e < En; ++e) {
            float w = Wi[row * En + e];
            sk = fmaf(w, Wk[e * An + col], sk);
            sq = fmaf(w, Wq[e * An + col], sq);
        }
        wikp[idx] = bf16_1(sk);
        wiqp[idx] = bf16_1(sq);
        if (idx < An) {
            float s = 0.f;
            for (int e = 0; e < En; ++e)
                s = fmaf(bi[e], Wq[e * An + idx] + Wk[e * An + idx], s);
            bq[idx] = s;
        }
    } else if (blk < 64) {
        pack_frag(Wi, wip, (blk - 32) * 256 + tid, 64, 4);
    } else if (blk < 160) {
        pack_frag(W1, w1p, (blk - 64) * 256 + tid, 128, 6);
    } else if (blk < 192) {
        pack_frag(W2, w2p, (blk - 160) * 256 + tid, 64, 4);
    } else if (blk < 200) {
        pack_frag(W3, w3p, (blk - 192) * 256 + tid, 32, 2);
    } else {
        if (tid < H1n) {
            float a = g1[tid] * rsqrtf(v1[tid] + EPSn);
            al1[tid] = a; bt1[tid] = (b1[tid] - m1[tid]) * a + be1[tid];
        } else if (tid < H1n + H2n) {
            int i = tid - H1n;
            float a = g2[i] * rsqrtf(v2[i] + EPSn);
            al2[i] = a; bt2[i] = (b2[i] - m2[i]) * a + be2[i];
        } else if (tid < H1n + H2n + H3n) {
            int i = tid - H1n - H2n;
            float a = g3[i] * rsqrtf(v3[i] + EPSn);
            al3[i] = a; bt3[i] = (b3[i] - m3[i]) * a + be3[i];
        }
    }
}

// ---------- K2: ce = bf16(cand@Wi + bi), qhb = cand@Wiq + bq  (64 rows/block) ----------
__global__ __launch_bounds__(256, 4) void k_embed(
    const float* __restrict__ cand, const ushort* __restrict__ wip,
    const ushort* __restrict__ wiqp, const float* __restrict__ bi,
    const float* __restrict__ bq, ushort* __restrict__ ce, float* __restrict__ qhb) {
    const int tid = threadIdx.x, wv = tid >> 6, lane = tid & 63;
    const int rb = blockIdx.x * 64;
    __shared__ uint c_l[64 * 64];
    for (int i = tid; i < 2048; i += 256) {
        int row = i >> 5, f4 = i & 31;
        float4 v = ((const float4*)(cand + (size_t)(rb + row) * Fn))[f4];
        uint2 pw; pw.x = pack_bf2(v.x, v.y); pw.y = pack_bf2(v.z, v.w);
        int dw = (2 * f4) ^ ((row & 7) << 2);
        *(uint2*)&c_l[row * 64 + dw] = pw;
    }
    __syncthreads();
    const int r = wv * 16 + (lane & 15);
    bf16x8 afr[4];
    #pragma unroll
    for (int k = 0; k < 4; ++k)
        afr[k] = *(const bf16x8*)&c_l[r * 64 + ((k * 16 + 4 * (lane >> 4)) ^ ((r & 7) << 2))];
    #pragma unroll
    for (int ct = 0; ct < 4; ++ct) {
        f32x4 acc = {0.f, 0.f, 0.f, 0.f};
        #pragma unroll
        for (int k = 0; k < 4; ++k) {
            bf16x8 bfr = *(const bf16x8*)&wip[((ct * 4 + k) * 64 + lane) * 8];
            acc = __builtin_amdgcn_mfma_f32_16x16x32_bf16(afr[k], bfr, acc, 0, 0, 0);
        }
        int col = ct * 16 + (lane & 15);
        float bic = bi[col];
        #pragma unroll
        for (int i = 0; i < 4; ++i) {
            int rg = rb + wv * 16 + (lane >> 4) * 4 + i;
            ce[(size_t)rg * 64 + col] = bf16_1(acc[i] + bic);
        }
    }
    #pragma unroll
    for (int ct = 0; ct < 4; ++ct) {
        f32x4 acc = {0.f, 0.f, 0.f, 0.f};
        #pragma unroll
        for (int k = 0; k < 4; ++k) {
            bf16x8 bfr = *(const bf16x8*)&wiqp[((ct * 4 + k) * 64 + lane) * 8];
            acc = __builtin_amdgcn_mfma_f32_16x16x32_bf16(afr[k], bfr, acc, 0, 0, 0);
        }
        int col = ct * 16 + (lane & 15);
        float bqc = bq[col];
        #pragma unroll
        for (int i = 0; i < 4; ++i) {
            int rg = rb + wv * 16 + (lane >> 4) * 4 + i;
            qhb[(size_t)rg * 64 + col] = acc[i] + bqc;
        }
    }
}

// ---------- K3: attention + pooling; R9 chassis, wik from GLOBAL, 5 blocks/CU ----------
__global__ __launch_bounds__(256, 5) void k_main(
    const float* __restrict__ hist, const int* __restrict__ hlen,
    const float* __restrict__ qhb, const float* __restrict__ Wv,
    const ushort* __restrict__ wikp, ushort* __restrict__ ifav) {
    const int b = blockIdx.x;
    const int tid = threadIdx.x, wv = tid >> 6, lane = tid & 63;
    __shared__ alignas(16) uint h_u[64 * 64];    // 16KB chunk; reused for merge
    __shared__ alignas(16) float w_sc[64];

    const int len = hlen[b];
    const float* hb = hist + (size_t)b * Sn * Fn;
    const int sl32 = tid >> 5;          // 0..7
    const int f4l = tid & 31;

    // ---- prefetch rows 32..63 of chunk 0 ----
    float4 pv[4];
    #pragma unroll
    for (int q = 0; q < 4; ++q) {
        int row = 32 + 8 * q + sl32;
        pv[q] = (row < len) ? ((const float4*)(hb + (size_t)row * Fn))[f4l]
                            : make_float4(0.f, 0.f, 0.f, 0.f);
    }
    float qhb_l[4], wv_l[4];
    #pragma unroll
    for (int ct = 0; ct < 4; ++ct) {
        qhb_l[ct] = qhb[(size_t)b * 64 + ct * 16 + (lane & 15)];
        wv_l[ct] = Wv[ct * 16 + (lane & 15)];
    }

    float m = -3.0e38f, d = 0.f;
    float accx = 0.f, accy = 0.f, sumx = 0.f, sumy = 0.f;
    const int nch = (len + 63) >> 6;

    for (int c = 0; c < nch; ++c) {
        const int sc0 = c * 64;
        // ---- stage rows 0..31 fused (load->pack->write) ----
        #pragma unroll
        for (int q = 0; q < 4; ++q) {
            int sl = 8 * q + sl32;
            int sg = sc0 + sl;
            float4 v = (sg < len) ? ((const float4*)(hb + (size_t)sg * Fn))[f4l]
                                  : make_float4(0.f, 0.f, 0.f, 0.f);
            uint2 pw;
            pw.x = pack_bf2(v.x, v.y);
            pw.y = pack_bf2(v.z, v.w);
            int dw = (2 * f4l) ^ ((sl & 7) << 2);
            *(uint2*)&h_u[sl * 64 + dw] = pw;
        }
        // ---- write rows 32..63 from prefetched pv ----
        #pragma unroll
        for (int q = 0; q < 4; ++q) {
            int sl = 32 + 8 * q + sl32;
            uint2 pw;
            pw.x = pack_bf2(pv[q].x, pv[q].y);
            pw.y = pack_bf2(pv[q].z, pv[q].w);
            int dw = (2 * f4l) ^ ((sl & 7) << 2);
            *(uint2*)&h_u[sl * 64 + dw] = pw;
        }
        // ---- issue prefetch of rows 32..63 for chunk c+1 ----
        if (c + 1 < nch) {
            const int nb = sc0 + 64 + 32;
            #pragma unroll
            for (int q = 0; q < 4; ++q) {
                int row = nb + 8 * q + sl32;
                pv[q] = (row < len) ? ((const float4*)(hb + (size_t)row * Fn))[f4l]
                                    : make_float4(0.f, 0.f, 0.f, 0.f);
            }
        }
        __syncthreads();                                    // B1: h_u ready
        // ---- scores via MFMA: wave wv owns rows [wv*16, wv*16+16); B from global ----
        {
            const int r = wv * 16 + (lane & 15);
            bf16x8 afr[4];
            #pragma unroll
            for (int k = 0; k < 4; ++k)
                afr[k] = *(const bf16x8*)&h_u[r * 64 + ((k * 16 + 4 * (lane >> 4)) ^ ((r & 7) << 2))];
            float contrib[4] = {0.f, 0.f, 0.f, 0.f};
            #pragma unroll
            for (int ct = 0; ct < 4; ++ct) {
                f32x4 acc = {0.f, 0.f, 0.f, 0.f};
                #pragma unroll
                for (int k = 0; k < 4; ++k) {
                    bf16x8 bfr = *(const bf16x8*)&wikp[((ct * 4 + k) * 64 + lane) * 8];
                    acc = __builtin_amdgcn_mfma_f32_16x16x32_bf16(afr[k], bfr, acc, 0, 0, 0);
                }
                float qv = qhb_l[ct], wvv = wv_l[ct];
                #pragma unroll
                for (int rr = 0; rr < 4; ++rr)
                    contrib[rr] += fmaxf(acc[rr] + qv, 0.f) * wvv;
            }
            #pragma unroll
            for (int o = 1; o < 16; o <<= 1) {
                #pragma unroll
                for (int rr = 0; rr < 4; ++rr)
                    contrib[rr] += __shfl_xor(contrib[rr], o, 64);
            }
            if ((lane & 15) == 0) {
                #pragma unroll
                for (int rr = 0; rr < 4; ++rr) {
                    int jr = wv * 16 + (lane >> 4) * 4 + rr;
                    w_sc[jr] = (sc0 + jr < len) ? contrib[rr] : -1e30f;
                }
            }
        }
        __syncthreads();                                    // B2: w_sc ready
        // ---- redundant per-wave softmax + guard-free pooling ----
        {
            const f32x4* wsp = (const f32x4*)w_sc;
            float mloc = -3.0e38f;
            #pragma unroll
            for (int q = 0; q < 16; ++q) {
                f32x4 s = wsp[q];
                mloc = fmaxf(mloc, fmaxf(fmaxf(s[0], s[1]), fmaxf(s[2], s[3])));
            }
            float mn = fmaxf(m, mloc);
            float cc = __expf(m - mn);
            m = mn;
            d *= cc; accx *= cc; accy *= cc;
            #pragma unroll
            for (int j = 0; j < 16; ++j) {
                int sl = 4 * j + wv;
                float wgt = __expf(w_sc[sl] - mn);          // 0 for invalid rows
                d += wgt;
                uint hv = h_u[sl * 64 + (lane ^ ((sl & 7) << 2))];
                float hx = __uint_as_float(hv << 16);
                float hy = __uint_as_float(hv & 0xffff0000u);
                accx = fmaf(wgt, hx, accx);
                accy = fmaf(wgt, hy, accy);
                sumx += hx; sumy += hy;
            }
        }
        __syncthreads();                                    // B3: protect h_u/w_sc
    }

    // ---- merge: overlay scratch on h_u (dead after last pool phase) ----
    float* mrg = (float*)h_u;   // [0:4) d, [8:520) acc, [520:1032) sum
    if (lane == 0) mrg[wv] = d;
    mrg[8 + wv * Fn + 2 * lane + 0] = accx;
    mrg[8 + wv * Fn + 2 * lane + 1] = accy;
    mrg[520 + wv * Fn + 2 * lane + 0] = sumx;
    mrg[520 + wv * Fn + 2 * lane + 1] = sumy;
    __syncthreads();
    if (tid < Fn) {
        float D = mrg[0] + mrg[1] + mrg[2] + mrg[3];
        float A = mrg[8 + tid] + mrg[8 + Fn + tid] + mrg[8 + 2 * Fn + tid] + mrg[8 + 3 * Fn + tid];
        float S = mrg[520 + tid] + mrg[520 + Fn + tid] + mrg[520 + 2 * Fn + tid] + mrg[520 + 3 * Fn + tid];
        ifav[(size_t)b * 256 + tid] = bf16_1(A / D);
        ifav[(size_t)b * 256 + 128 + tid] = bf16_1(S / (float)len);
    }
}

// ---------- K4: projection + MLP + sigmoid. 64 rows/block ----------
__global__ __launch_bounds__(256, 2) void k_mlp(
    const ushort* __restrict__ ifav, const ushort* __restrict__ ce,
    const float* __restrict__ bi, const ushort* __restrict__ wip,
    const ushort* __restrict__ w1p, const ushort* __restrict__ w2p,
    const ushort* __restrict__ w3p,
    const float* __restrict__ al1, const float* __restrict__ bt1,
    const float* __restrict__ al2, const float* __restrict__ bt2,
    const float* __restrict__ al3, const float* __restrict__ bt3,
    const float* __restrict__ Wo, const float* __restrict__ bo,
    float* __restrict__ out) {
    const int tid = threadIdx.x, wv = tid >> 6, lane = tid & 63;
    const int rb = blockIdx.x * 64;
    __shared__ uint x_l[64 * 96];
    __shared__ uint h1_l[64 * 64];
    __shared__ uint h2_l[64 * 32];
    __shared__ uint h3_l[64 * 16];
    ushort* x_s = (ushort*)x_l;
    ushort* h1_s = (ushort*)h1_l;
    ushort* h2_s = (ushort*)h2_l;
    ushort* h3_s = (ushort*)h3_l;

    const int rloc = wv * 16 + (lane & 15);

    #pragma unroll
    for (int half = 0; half < 2; ++half) {
        bf16x8 afr[4];
        #pragma unroll
        for (int k = 0; k < 4; ++k)
            afr[k] = *(const bf16x8*)&ifav[(size_t)(rb + rloc) * 256 + half * 128 + k * 32 + 8 * (lane >> 4)];
        #pragma unroll
        for (int ct = 0; ct < 4; ++ct) {
            f32x4 acc = {0.f, 0.f, 0.f, 0.f};
            #pragma unroll
            for (int k = 0; k < 4; ++k) {
                bf16x8 bfr = *(const bf16x8*)&wip[((ct * 4 + k) * 64 + lane) * 8];
                acc = __builtin_amdgcn_mfma_f32_16x16x32_bf16(afr[k], bfr, acc, 0, 0, 0);
            }
            int col = ct * 16 + (lane & 15);
            float bic = bi[col];
            int xcol = half * 128 + col;
            #pragma unroll
            for (int i = 0; i < 4; ++i) {
                int row = wv * 16 + (lane >> 4) * 4 + i;
                int dd = (xcol >> 1) ^ ((row & 7) << 2);
                x_s[(row * 96 + dd) * 2 + (xcol & 1)] = bf16_1(acc[i] + bic);
            }
        }
    }
    {
        int rl = wv * 16 + (lane >> 2);
        int colb = (lane & 3) * 16;
        #pragma unroll
        for (int u = 0; u < 2; ++u) {
            uint4 v = *(const uint4*)&ce[(size_t)(rb + rl) * 64 + colb + u * 8];
            int db = (32 + (lane & 3) * 8 + u * 4) ^ ((rl & 7) << 2);
            *(uint4*)&x_l[rl * 96 + db] = v;
        }
    }
    {
        bf16x8 xa[6];
        #pragma unroll
        for (int k = 0; k < 6; ++k)
            xa[k] = *(const bf16x8*)&x_l[rloc * 96 + ((k * 16 + 4 * (lane >> 4)) ^ ((rloc & 7) << 2))];
        #pragma unroll
        for (int ct = 0; ct < 8; ++ct) {
            f32x4 acc = {0.f, 0.f, 0.f, 0.f};
            #pragma unroll
            for (int k = 0; k < 6; ++k) {
                bf16x8 bfr = *(const bf16x8*)&w1p[((ct * 6 + k) * 64 + lane) * 8];
                acc = __builtin_amdgcn_mfma_f32_16x16x32_bf16(xa[k], bfr, acc, 0, 0, 0);
            }
            int col = ct * 16 + (lane & 15);
            float a = al1[col], bt = bt1[col];
            #pragma unroll
            for (int i = 0; i < 4; ++i) {
                int row = wv * 16 + (lane >> 4) * 4 + i;
                float hv = fmaxf(fmaf(acc[i], a, bt), 0.f);
                int dd = (col >> 1) ^ ((row & 7) << 2);
                h1_s[(row * 64 + dd) * 2 + (col & 1)] = bf16_1(hv);
            }
        }
    }
    {
        bf16x8 xa[4];
        #pragma unroll
        for (int k = 0; k < 4; ++k)
            xa[k] = *(const bf16x8*)&h1_l[rloc * 64 + ((k * 16 + 4 * (lane >> 4)) ^ ((rloc & 7) << 2))];
        #pragma unroll
        for (int ct = 0; ct < 4; ++ct) {
            f32x4 acc = {0.f, 0.f, 0.f, 0.f};
            #pragma unroll
            for (int k = 0; k < 4; ++k) {
                bf16x8 bfr = *(const bf16x8*)&w2p[((ct * 4 + k) * 64 + lane) * 8];
                acc = __builtin_amdgcn_mfma_f32_16x16x32_bf16(xa[k], bfr, acc, 0, 0, 0);
            }
            int col = ct * 16 + (lane & 15);
            float a = al2[col], bt = bt2[col];
            #pragma unroll
            for (int i = 0; i < 4; ++i) {
                int row = wv * 16 + (lane >> 4) * 4 + i;
                float hv = fmaxf(fmaf(acc[i], a, bt), 0.f);
                int dd = (col >> 1) ^ ((row & 7) << 2);
                h2_s[(row * 32 + dd) * 2 + (col & 1)] = bf16_1(hv);
            }
        }
    }
    {
        bf16x8 xa[2];
        #pragma unroll
        for (int k = 0; k < 2; ++k)
            xa[k] = *(const bf16x8*)&h2_l[rloc * 32 + ((k * 16 + 4 * (lane >> 4)) ^ ((rloc & 7) << 2))];
        #pragma unroll
        for (int ct = 0; ct < 2; ++ct) {
            f32x4 acc = {0.f, 0.f, 0.f, 0.f};
            #pragma unroll
            for (int k = 0; k < 2; ++k) {
                bf16x8 bfr = *(const bf16x8*)&w3p[((ct * 2 + k) * 64 + lane) * 8];
                acc = __builtin_amdgcn_mfma_f32_16x16x32_bf16(xa[k], bfr, acc, 0, 0, 0);
            }
            int col = ct * 16 + (lane & 15);
            float a = al3[col], bt = bt3[col];
            #pragma unroll
            for (int i = 0; i < 4; ++i) {
                int row = wv * 16 + (lane >> 4) * 4 + i;
                float hv = fmaxf(fmaf(acc[i], a, bt), 0.f);
                int dd = (col >> 1) ^ ((row & 3) << 2);
                h3_s[(row * 16 + dd) * 2 + (col & 1)] = bf16_1(hv);
            }
        }
    }
    if (lane < 16) {
        int row = wv * 16 + lane;
        float acc = bo[0];
        #pragma unroll
        for (int dd = 0; dd < 16; ++dd) {
            uint hv = h3_l[row * 16 + (dd ^ ((row & 3) << 2))];
            float h0 = __uint_as_float(hv << 16);
            float h1 = __uint_as_float(hv & 0xffff0000u);
            acc = fmaf(h0, Wo[2 * dd], fmaf(h1, Wo[2 * dd + 1], acc));
        }
        out[rb + row] = 1.f / (1.f + __expf(-acc));
    }
}

extern "C" void kernel_launch(void* const* d_in, const int* in_sizes, int n_in,
                              void* d_out, int out_size, void* d_ws, size_t ws_size,
                              hipStream_t stream) {
    const float* cand = (const float*)d_in[0];
    const float* hist = (const float*)d_in[1];
    const int*   hlen = (const int*)d_in[2];
    const float* Wi = (const float*)d_in[3];
    const float* bi = (const float*)d_in[4];
    const float* Wq = (const float*)d_in[5];
    const float* Wk = (const float*)d_in[6];
    const float* Wv = (const float*)d_in[7];
    const float* W1 = (const float*)d_in[8];
    const float* b1 = (const float*)d_in[9];
    const float* g1 = (const float*)d_in[10];
    const float* be1 = (const float*)d_in[11];
    const float* m1 = (const float*)d_in[12];
    const float* v1 = (const float*)d_in[13];
    const float* W2 = (const float*)d_in[14];
    const float* b2 = (const float*)d_in[15];
    const float* g2 = (const float*)d_in[16];
    const float* be2 = (const float*)d_in[17];
    const float* m2 = (const float*)d_in[18];
    const float* v2 = (const float*)d_in[19];
    const float* W3 = (const float*)d_in[20];
    const float* b3 = (const float*)d_in[21];
    const float* g3 = (const float*)d_in[22];
    const float* be3 = (const float*)d_in[23];
    const float* m3 = (const float*)d_in[24];
    const float* v3 = (const float*)d_in[25];
    const float* Wo = (const float*)d_in[26];
    const float* bo = (const float*)d_in[27];
    float* out = (float*)d_out;

    char* ws = (char*)d_ws;
    ushort* wikp = (ushort*)(ws + 0);
    ushort* wiqp = (ushort*)(ws + 16384);
    ushort* wip  = (ushort*)(ws + 32768);
    ushort* w1p  = (ushort*)(ws + 49152);
    ushort* w2p  = (ushort*)(ws + 98304);
    ushort* w3p  = (ushort*)(ws + 114688);
    float*  bq   = (float*)(ws + 118784);
    float*  al1  = (float*)(ws + 119040);
    float*  bt1  = (float*)(ws + 119552);
    float*  al2  = (float*)(ws + 120064);
    float*  bt2  = (float*)(ws + 120320);
    float*  al3  = (float*)(ws + 120576);
    float*  bt3  = (float*)(ws + 120704);
    float*  qhb  = (float*)(ws + 131072);              // 2 MB
    ushort* ce   = (ushort*)(ws + 131072 + 2097152);   // 1 MB
    ushort* ifav = (ushort*)(ws + 131072 + 3145728);   // 4 MB

    k_prep<<<201, 256, 0, stream>>>(Wi, bi, Wk, Wq, W1, W2, W3,
                                    b1, g1, be1, m1, v1,
                                    b2, g2, be2, m2, v2,
                                    b3, g3, be3, m3, v3,
                                    wikp, wiqp, bq, wip, w1p, w2p, w3p,
                                    al1, bt1, al2, bt2, al3, bt3);
    k_embed<<<Bn / 64, 256, 0, stream>>>(cand, wip, wiqp, bi, bq, ce, qhb);
    k_main<<<Bn, 256, 0, stream>>>(hist, hlen, qhb, Wv, wikp, ifav);
    k_mlp<<<Bn / 64, 256, 0, stream>>>(ifav, ce, bi, wip, w1p, w2p, w3p,
                                       al1, bt1, al2, bt2, al3, bt3, Wo, bo, out);
}

// Round 14
// 155.761 us; speedup vs baseline: 2.9151x; 2.9151x over previous
//
#include <hip/hip_runtime.h>
#include <math.h>

#define Bn 8192
#define Sn 200
#define Fn 128
#define En 64
#define An 64
#define H1n 128
#define H2n 64
#define H3n 32
#define EPSn 1e-5f

typedef __attribute__((ext_vector_type(8))) short bf16x8;
typedef __attribute__((ext_vector_type(4))) float f32x4;

// raw barrier: waits own DS ops, does NOT drain vmcnt (prefetch stays in flight)
#define BARR() do { asm volatile("s_waitcnt lgkmcnt(0)" ::: "memory"); \
                    __builtin_amdgcn_s_barrier(); \
                    asm volatile("" ::: "memory"); } while (0)

__device__ __forceinline__ uint pack_bf2(float a, float b) {
    uint ua = __float_as_uint(a), ub = __float_as_uint(b);
    ua += 0x7fffu + ((ua >> 16) & 1u);
    ub += 0x7fffu + ((ub >> 16) & 1u);
    return (ua >> 16) | (ub & 0xffff0000u);
}
__device__ __forceinline__ ushort bf16_1(float a) {
    uint u = __float_as_uint(a);
    u += 0x7fffu + ((u >> 16) & 1u);
    return (ushort)(u >> 16);
}

__device__ __forceinline__ void pack_frag(const float* __restrict__ src,
                                          ushort* __restrict__ dst,
                                          int p, int N, int nk) {
    int j = p & 7, l = (p >> 3) & 63, t = p >> 9;
    int k = t % nk, ct = t / nk;
    int row = k * 32 + 8 * (l >> 4) + j;
    int col = ct * 16 + (l & 15);
    dst[p] = bf16_1(src[row * N + col]);
}

// ---------- K1: all weight prep in ONE kernel (201 blocks) ----------
__global__ void k_prep(
    const float* __restrict__ Wi, const float* __restrict__ bi,
    const float* __restrict__ Wk, const float* __restrict__ Wq,
    const float* __restrict__ W1, const float* __restrict__ W2,
    const float* __restrict__ W3,
    const float* __restrict__ b1, const float* __restrict__ g1,
    const float* __restrict__ be1, const float* __restrict__ m1,
    const float* __restrict__ v1,
    const float* __restrict__ b2, const float* __restrict__ g2,
    const float* __restrict__ be2, const float* __restrict__ m2,
    const float* __restrict__ v2,
    const float* __restrict__ b3, const float* __restrict__ g3,
    const float* __restrict__ be3, const float* __restrict__ m3,
    const float* __restrict__ v3,
    ushort* __restrict__ wikp, ushort* __restrict__ wiqp, float* __restrict__ bq,
    ushort* __restrict__ wip, ushort* __restrict__ w1p,
    ushort* __restrict__ w2p, ushort* __restrict__ w3p,
    float* __restrict__ al1, float* __restrict__ bt1,
    float* __restrict__ al2, float* __restrict__ bt2,
    float* __restrict__ al3, float* __restrict__ bt3) {
    const int blk = blockIdx.x, tid = threadIdx.x;
    if (blk < 32) {
        int idx = blk * 256 + tid;
        int j = idx & 7, l = (idx >> 3) & 63, t = idx >> 9;
        int k = t & 3, ct = t >> 2;
        int row = k * 32 + 8 * (l >> 4) + j;
        int col = ct * 16 + (l & 15);
        float sk = 0.f, sq = 0.f;
        for (int e = 0; e < En; ++e) {
            float w = Wi[row * En + e];
            sk = fmaf(w, Wk[e * An + col], sk);
            sq = fmaf(w, Wq[e * An + col], sq);
        }
        wikp[idx] = bf16_1(sk);
        wiqp[idx] = bf16_1(sq);
        if (idx < An) {
            float s = 0.f;
            for (int e = 0; e < En; ++e)
                s = fmaf(bi[e], Wq[e * An + idx] + Wk[e * An + idx], s);
            bq[idx] = s;
        }
    } else if (blk < 64) {
        pack_frag(Wi, wip, (blk - 32) * 256 + tid, 64, 4);
    } else if (blk < 160) {
        pack_frag(W1, w1p, (blk - 64) * 256 + tid, 128, 6);
    } else if (blk < 192) {
        pack_frag(W2, w2p, (blk - 160) * 256 + tid, 64, 4);
    } else if (blk < 200) {
        pack_frag(W3, w3p, (blk - 192) * 256 + tid, 32, 2);
    } else {
        if (tid < H1n) {
            float a = g1[tid] * rsqrtf(v1[tid] + EPSn);
            al1[tid] = a; bt1[tid] = (b1[tid] - m1[tid]) * a + be1[tid];
        } else if (tid < H1n + H2n) {
            int i = tid - H1n;
            float a = g2[i] * rsqrtf(v2[i] + EPSn);
            al2[i] = a; bt2[i] = (b2[i] - m2[i]) * a + be2[i];
        } else if (tid < H1n + H2n + H3n) {
            int i = tid - H1n - H2n;
            float a = g3[i] * rsqrtf(v3[i] + EPSn);
            al3[i] = a; bt3[i] = (b3[i] - m3[i]) * a + be3[i];
        }
    }
}

// ---------- K2: ce = bf16(cand@Wi + bi), qhb = cand@Wiq + bq  (64 rows/block) ----------
__global__ __launch_bounds__(256, 4) void k_embed(
    const float* __restrict__ cand, const ushort* __restrict__ wip,
    const ushort* __restrict__ wiqp, const float* __restrict__ bi,
    const float* __restrict__ bq, ushort* __restrict__ ce, float* __restrict__ qhb) {
    const int tid = threadIdx.x, wv = tid >> 6, lane = tid & 63;
    const int rb = blockIdx.x * 64;
    __shared__ uint c_l[64 * 64];
    for (int i = tid; i < 2048; i += 256) {
        int row = i >> 5, f4 = i & 31;
        float4 v = ((const float4*)(cand + (size_t)(rb + row) * Fn))[f4];
        uint2 pw; pw.x = pack_bf2(v.x, v.y); pw.y = pack_bf2(v.z, v.w);
        int dw = (2 * f4) ^ ((row & 7) << 2);
        *(uint2*)&c_l[row * 64 + dw] = pw;
    }
    __syncthreads();
    const int r = wv * 16 + (lane & 15);
    bf16x8 afr[4];
    #pragma unroll
    for (int k = 0; k < 4; ++k)
        afr[k] = *(const bf16x8*)&c_l[r * 64 + ((k * 16 + 4 * (lane >> 4)) ^ ((r & 7) << 2))];
    #pragma unroll
    for (int ct = 0; ct < 4; ++ct) {
        f32x4 acc = {0.f, 0.f, 0.f, 0.f};
        #pragma unroll
        for (int k = 0; k < 4; ++k) {
            bf16x8 bfr = *(const bf16x8*)&wip[((ct * 4 + k) * 64 + lane) * 8];
            acc = __builtin_amdgcn_mfma_f32_16x16x32_bf16(afr[k], bfr, acc, 0, 0, 0);
        }
        int col = ct * 16 + (lane & 15);
        float bic = bi[col];
        #pragma unroll
        for (int i = 0; i < 4; ++i) {
            int rg = rb + wv * 16 + (lane >> 4) * 4 + i;
            ce[(size_t)rg * 64 + col] = bf16_1(acc[i] + bic);
        }
    }
    #pragma unroll
    for (int ct = 0; ct < 4; ++ct) {
        f32x4 acc = {0.f, 0.f, 0.f, 0.f};
        #pragma unroll
        for (int k = 0; k < 4; ++k) {
            bf16x8 bfr = *(const bf16x8*)&wiqp[((ct * 4 + k) * 64 + lane) * 8];
            acc = __builtin_amdgcn_mfma_f32_16x16x32_bf16(afr[k], bfr, acc, 0, 0, 0);
        }
        int col = ct * 16 + (lane & 15);
        float bqc = bq[col];
        #pragma unroll
        for (int i = 0; i < 4; ++i) {
            int rg = rb + wv * 16 + (lane >> 4) * 4 + i;
            qhb[(size_t)rg * 64 + col] = acc[i] + bqc;
        }
    }
}

// ---------- K3: attention + pooling; full register prefetch, lgkm-only barriers ----------
__global__ __launch_bounds__(256, 4) void k_main(
    const float* __restrict__ hist, const int* __restrict__ hlen,
    const float* __restrict__ qhb, const float* __restrict__ Wv,
    const ushort* __restrict__ wikp, ushort* __restrict__ ifav) {
    const int b = blockIdx.x;
    const int tid = threadIdx.x, wv = tid >> 6, lane = tid & 63;
    __shared__ uint wik_l[4096];                 // 16KB B frags; reused for merge
    __shared__ alignas(16) uint h_u[64 * 64];    // 16KB chunk
    __shared__ alignas(16) float w_sc[64];

    const int len = hlen[b];
    const float* hb = hist + (size_t)b * Sn * Fn;
    const int sl32 = tid >> 5;          // 0..7
    const int f4l = tid & 31;

    // ---- prologue: prefetch BOTH halves of chunk 0 (hides under wik staging) ----
    float4 pvA[4], pvB[4];
    #pragma unroll
    for (int q = 0; q < 4; ++q) {
        int rowA = 8 * q + sl32;
        pvA[q] = (rowA < len) ? ((const float4*)(hb + (size_t)rowA * Fn))[f4l]
                              : make_float4(0.f, 0.f, 0.f, 0.f);
    }
    #pragma unroll
    for (int q = 0; q < 4; ++q) {
        int rowB = 32 + 8 * q + sl32;
        pvB[q] = (rowB < len) ? ((const float4*)(hb + (size_t)rowB * Fn))[f4l]
                              : make_float4(0.f, 0.f, 0.f, 0.f);
    }
    // ---- stage packed Wik -> LDS (swizzled) ----
    {
        const uint4* wp = (const uint4*)wikp;
        for (int q = tid; q < 1024; q += 256) {
            uint4 v = wp[q];
            int l = q & 63;
            int dw = (q * 4) ^ (((l >> 3) & 3) << 2);
            *(uint4*)&wik_l[dw] = v;
        }
    }
    float qhb_l[4], wv_l[4];
    #pragma unroll
    for (int ct = 0; ct < 4; ++ct) {
        qhb_l[ct] = qhb[(size_t)b * 64 + ct * 16 + (lane & 15)];
        wv_l[ct] = Wv[ct * 16 + (lane & 15)];
    }

    float m = -3.0e38f, d = 0.f;
    float accx = 0.f, accy = 0.f, sumx = 0.f, sumy = 0.f;
    const int nch = (len + 63) >> 6;

    for (int c = 0; c < nch; ++c) {
        const int sc0 = c * 64;
        // ---- stage: ALL writes from registers (no in-phase loads) ----
        #pragma unroll
        for (int q = 0; q < 4; ++q) {
            int sl = 8 * q + sl32;
            uint2 pw;
            pw.x = pack_bf2(pvA[q].x, pvA[q].y);
            pw.y = pack_bf2(pvA[q].z, pvA[q].w);
            int dw = (2 * f4l) ^ ((sl & 7) << 2);
            *(uint2*)&h_u[sl * 64 + dw] = pw;
        }
        #pragma unroll
        for (int q = 0; q < 4; ++q) {
            int sl = 32 + 8 * q + sl32;
            uint2 pw;
            pw.x = pack_bf2(pvB[q].x, pvB[q].y);
            pw.y = pack_bf2(pvB[q].z, pvB[q].w);
            int dw = (2 * f4l) ^ ((sl & 7) << 2);
            *(uint2*)&h_u[sl * 64 + dw] = pw;
        }
        // ---- issue pvA for chunk c+1 (covered by score phase + barriers) ----
        if (c + 1 < nch) {
            const int nb = sc0 + 64;
            #pragma unroll
            for (int q = 0; q < 4; ++q) {
                int row = nb + 8 * q + sl32;
                pvA[q] = (row < len) ? ((const float4*)(hb + (size_t)row * Fn))[f4l]
                                     : make_float4(0.f, 0.f, 0.f, 0.f);
            }
        }
        BARR();                                             // B1: h_u ready (no vmcnt drain)
        // ---- scores via MFMA: wave wv owns rows [wv*16, wv*16+16) ----
        {
            const int r = wv * 16 + (lane & 15);
            bf16x8 afr[4];
            #pragma unroll
            for (int k = 0; k < 4; ++k)
                afr[k] = *(const bf16x8*)&h_u[r * 64 + ((k * 16 + 4 * (lane >> 4)) ^ ((r & 7) << 2))];
            float contrib[4] = {0.f, 0.f, 0.f, 0.f};
            #pragma unroll
            for (int ct = 0; ct < 4; ++ct) {
                f32x4 acc = {0.f, 0.f, 0.f, 0.f};
                #pragma unroll
                for (int k = 0; k < 4; ++k) {
                    bf16x8 bfr = *(const bf16x8*)&wik_l[(((ct * 4 + k) * 64 + lane) * 4) ^ (((lane >> 3) & 3) << 2)];
                    acc = __builtin_amdgcn_mfma_f32_16x16x32_bf16(afr[k], bfr, acc, 0, 0, 0);
                }
                float qv = qhb_l[ct], wvv = wv_l[ct];
                #pragma unroll
                for (int rr = 0; rr < 4; ++rr)
                    contrib[rr] += fmaxf(acc[rr] + qv, 0.f) * wvv;
            }
            #pragma unroll
            for (int o = 1; o < 16; o <<= 1) {
                #pragma unroll
                for (int rr = 0; rr < 4; ++rr)
                    contrib[rr] += __shfl_xor(contrib[rr], o, 64);
            }
            if ((lane & 15) == 0) {
                #pragma unroll
                for (int rr = 0; rr < 4; ++rr) {
                    int jr = wv * 16 + (lane >> 4) * 4 + rr;
                    w_sc[jr] = (sc0 + jr < len) ? contrib[rr] : -1e30f;
                }
            }
        }
        BARR();                                             // B2: w_sc ready
        // ---- issue pvB for chunk c+1 (covered by pool phase + B3) ----
        if (c + 1 < nch) {
            const int nb = sc0 + 64 + 32;
            #pragma unroll
            for (int q = 0; q < 4; ++q) {
                int row = nb + 8 * q + sl32;
                pvB[q] = (row < len) ? ((const float4*)(hb + (size_t)row * Fn))[f4l]
                                     : make_float4(0.f, 0.f, 0.f, 0.f);
            }
        }
        // ---- redundant per-wave softmax + guard-free pooling ----
        {
            const f32x4* wsp = (const f32x4*)w_sc;
            float mloc = -3.0e38f;
            #pragma unroll
            for (int q = 0; q < 16; ++q) {
                f32x4 s = wsp[q];
                mloc = fmaxf(mloc, fmaxf(fmaxf(s[0], s[1]), fmaxf(s[2], s[3])));
            }
            float mn = fmaxf(m, mloc);
            float cc = __expf(m - mn);
            m = mn;
            d *= cc; accx *= cc; accy *= cc;
            #pragma unroll
            for (int j = 0; j < 16; ++j) {
                int sl = 4 * j + wv;
                float wgt = __expf(w_sc[sl] - mn);          // 0 for invalid rows
                d += wgt;
                uint hv = h_u[sl * 64 + (lane ^ ((sl & 7) << 2))];
                float hx = __uint_as_float(hv << 16);
                float hy = __uint_as_float(hv & 0xffff0000u);
                accx = fmaf(wgt, hx, accx);
                accy = fmaf(wgt, hy, accy);
                sumx += hx; sumy += hy;
            }
        }
        BARR();                                             // B3: protect h_u/w_sc
    }

    // ---- merge: overlay scratch on wik_l (dead after last score phase) ----
    float* mrg = (float*)wik_l;   // [0:4) d, [8:520) acc, [520:1032) sum
    if (lane == 0) mrg[wv] = d;
    mrg[8 + wv * Fn + 2 * lane + 0] = accx;
    mrg[8 + wv * Fn + 2 * lane + 1] = accy;
    mrg[520 + wv * Fn + 2 * lane + 0] = sumx;
    mrg[520 + wv * Fn + 2 * lane + 1] = sumy;
    __syncthreads();
    if (tid < Fn) {
        float D = mrg[0] + mrg[1] + mrg[2] + mrg[3];
        float A = mrg[8 + tid] + mrg[8 + Fn + tid] + mrg[8 + 2 * Fn + tid] + mrg[8 + 3 * Fn + tid];
        float S = mrg[520 + tid] + mrg[520 + Fn + tid] + mrg[520 + 2 * Fn + tid] + mrg[520 + 3 * Fn + tid];
        ifav[(size_t)b * 256 + tid] = bf16_1(A / D);
        ifav[(size_t)b * 256 + 128 + tid] = bf16_1(S / (float)len);
    }
}

// ---------- K4: projection + MLP + sigmoid. 64 rows/block ----------
__global__ __launch_bounds__(256, 2) void k_mlp(
    const ushort* __restrict__ ifav, const ushort* __restrict__ ce,
    const float* __restrict__ bi, const ushort* __restrict__ wip,
    const ushort* __restrict__ w1p, const ushort* __restrict__ w2p,
    const ushort* __restrict__ w3p,
    const float* __restrict__ al1, const float* __restrict__ bt1,
    const float* __restrict__ al2, const float* __restrict__ bt2,
    const float* __restrict__ al3, const float* __restrict__ bt3,
    const float* __restrict__ Wo, const float* __restrict__ bo,
    float* __restrict__ out) {
    const int tid = threadIdx.x, wv = tid >> 6, lane = tid & 63;
    const int rb = blockIdx.x * 64;
    __shared__ uint x_l[64 * 96];
    __shared__ uint h1_l[64 * 64];
    __shared__ uint h2_l[64 * 32];
    __shared__ uint h3_l[64 * 16];
    ushort* x_s = (ushort*)x_l;
    ushort* h1_s = (ushort*)h1_l;
    ushort* h2_s = (ushort*)h2_l;
    ushort* h3_s = (ushort*)h3_l;

    const int rloc = wv * 16 + (lane & 15);

    #pragma unroll
    for (int half = 0; half < 2; ++half) {
        bf16x8 afr[4];
        #pragma unroll
        for (int k = 0; k < 4; ++k)
            afr[k] = *(const bf16x8*)&ifav[(size_t)(rb + rloc) * 256 + half * 128 + k * 32 + 8 * (lane >> 4)];
        #pragma unroll
        for (int ct = 0; ct < 4; ++ct) {
            f32x4 acc = {0.f, 0.f, 0.f, 0.f};
            #pragma unroll
            for (int k = 0; k < 4; ++k) {
                bf16x8 bfr = *(const bf16x8*)&wip[((ct * 4 + k) * 64 + lane) * 8];
                acc = __builtin_amdgcn_mfma_f32_16x16x32_bf16(afr[k], bfr, acc, 0, 0, 0);
            }
            int col = ct * 16 + (lane & 15);
            float bic = bi[col];
            int xcol = half * 128 + col;
            #pragma unroll
            for (int i = 0; i < 4; ++i) {
                int row = wv * 16 + (lane >> 4) * 4 + i;
                int dd = (xcol >> 1) ^ ((row & 7) << 2);
                x_s[(row * 96 + dd) * 2 + (xcol & 1)] = bf16_1(acc[i] + bic);
            }
        }
    }
    {
        int rl = wv * 16 + (lane >> 2);
        int colb = (lane & 3) * 16;
        #pragma unroll
        for (int u = 0; u < 2; ++u) {
            uint4 v = *(const uint4*)&ce[(size_t)(rb + rl) * 64 + colb + u * 8];
            int db = (32 + (lane & 3) * 8 + u * 4) ^ ((rl & 7) << 2);
            *(uint4*)&x_l[rl * 96 + db] = v;
        }
    }
    {
        bf16x8 xa[6];
        #pragma unroll
        for (int k = 0; k < 6; ++k)
            xa[k] = *(const bf16x8*)&x_l[rloc * 96 + ((k * 16 + 4 * (lane >> 4)) ^ ((rloc & 7) << 2))];
        #pragma unroll
        for (int ct = 0; ct < 8; ++ct) {
            f32x4 acc = {0.f, 0.f, 0.f, 0.f};
            #pragma unroll
            for (int k = 0; k < 6; ++k) {
                bf16x8 bfr = *(const bf16x8*)&w1p[((ct * 6 + k) * 64 + lane) * 8];
                acc = __builtin_amdgcn_mfma_f32_16x16x32_bf16(xa[k], bfr, acc, 0, 0, 0);
            }
            int col = ct * 16 + (lane & 15);
            float a = al1[col], bt = bt1[col];
            #pragma unroll
            for (int i = 0; i < 4; ++i) {
                int row = wv * 16 + (lane >> 4) * 4 + i;
                float hv = fmaxf(fmaf(acc[i], a, bt), 0.f);
                int dd = (col >> 1) ^ ((row & 7) << 2);
                h1_s[(row * 64 + dd) * 2 + (col & 1)] = bf16_1(hv);
            }
        }
    }
    {
        bf16x8 xa[4];
        #pragma unroll
        for (int k = 0; k < 4; ++k)
            xa[k] = *(const bf16x8*)&h1_l[rloc * 64 + ((k * 16 + 4 * (lane >> 4)) ^ ((rloc & 7) << 2))];
        #pragma unroll
        for (int ct = 0; ct < 4; ++ct) {
            f32x4 acc = {0.f, 0.f, 0.f, 0.f};
            #pragma unroll
            for (int k = 0; k < 4; ++k) {
                bf16x8 bfr = *(const bf16x8*)&w2p[((ct * 4 + k) * 64 + lane) * 8];
                acc = __builtin_amdgcn_mfma_f32_16x16x32_bf16(xa[k], bfr, acc, 0, 0, 0);
            }
            int col = ct * 16 + (lane & 15);
            float a = al2[col], bt = bt2[col];
            #pragma unroll
            for (int i = 0; i < 4; ++i) {
                int row = wv * 16 + (lane >> 4) * 4 + i;
                float hv = fmaxf(fmaf(acc[i], a, bt), 0.f);
                int dd = (col >> 1) ^ ((row & 7) << 2);
                h2_s[(row * 32 + dd) * 2 + (col & 1)] = bf16_1(hv);
            }
        }
    }
    {
        bf16x8 xa[2];
        #pragma unroll
        for (int k = 0; k < 2; ++k)
            xa[k] = *(const bf16x8*)&h2_l[rloc * 32 + ((k * 16 + 4 * (lane >> 4)) ^ ((rloc & 7) << 2))];
        #pragma unroll
        for (int ct = 0; ct < 2; ++ct) {
            f32x4 acc = {0.f, 0.f, 0.f, 0.f};
            #pragma unroll
            for (int k = 0; k < 2; ++k) {
                bf16x8 bfr = *(const bf16x8*)&w3p[((ct * 2 + k) * 64 + lane) * 8];
                acc = __builtin_amdgcn_mfma_f32_16x16x32_bf16(xa[k], bfr, acc, 0, 0, 0);
            }
            int col = ct * 16 + (lane & 15);
            float a = al3[col], bt = bt3[col];
            #pragma unroll
            for (int i = 0; i < 4; ++i) {
                int row = wv * 16 + (lane >> 4) * 4 + i;
                float hv = fmaxf(fmaf(acc[i], a, bt), 0.f);
                int dd = (col >> 1) ^ ((row & 3) << 2);
                h3_s[(row * 16 + dd) * 2 + (col & 1)] = bf16_1(hv);
            }
        }
    }
    if (lane < 16) {
        int row = wv * 16 + lane;
        float acc = bo[0];
        #pragma unroll
        for (int dd = 0; dd < 16; ++dd) {
            uint hv = h3_l[row * 16 + (dd ^ ((row & 3) << 2))];
            float h0 = __uint_as_float(hv << 16);
            float h1 = __uint_as_float(hv & 0xffff0000u);
            acc = fmaf(h0, Wo[2 * dd], fmaf(h1, Wo[2 * dd + 1], acc));
        }
        out[rb + row] = 1.f / (1.f + __expf(-acc));
    }
}

extern "C" void kernel_launch(void* const* d_in, const int* in_sizes, int n_in,
                              void* d_out, int out_size, void* d_ws, size_t ws_size,
                              hipStream_t stream) {
    const float* cand = (const float*)d_in[0];
    const float* hist = (const float*)d_in[1];
    const int*   hlen = (const int*)d_in[2];
    const float* Wi = (const float*)d_in[3];
    const float* bi = (const float*)d_in[4];
    const float* Wq = (const float*)d_in[5];
    const float* Wk = (const float*)d_in[6];
    const float* Wv = (const float*)d_in[7];
    const float* W1 = (const float*)d_in[8];
    const float* b1 = (const float*)d_in[9];
    const float* g1 = (const float*)d_in[10];
    const float* be1 = (const float*)d_in[11];
    const float* m1 = (const float*)d_in[12];
    const float* v1 = (const float*)d_in[13];
    const float* W2 = (const float*)d_in[14];
    const float* b2 = (const float*)d_in[15];
    const float* g2 = (const float*)d_in[16];
    const float* be2 = (const float*)d_in[17];
    const float* m2 = (const float*)d_in[18];
    const float* v2 = (const float*)d_in[19];
    const float* W3 = (const float*)d_in[20];
    const float* b3 = (const float*)d_in[21];
    const float* g3 = (const float*)d_in[22];
    const float* be3 = (const float*)d_in[23];
    const float* m3 = (const float*)d_in[24];
    const float* v3 = (const float*)d_in[25];
    const float* Wo = (const float*)d_in[26];
    const float* bo = (const float*)d_in[27];
    float* out = (float*)d_out;

    char* ws = (char*)d_ws;
    ushort* wikp = (ushort*)(ws + 0);
    ushort* wiqp = (ushort*)(ws + 16384);
    ushort* wip  = (ushort*)(ws + 32768);
    ushort* w1p  = (ushort*)(ws + 49152);
    ushort* w2p  = (ushort*)(ws + 98304);
    ushort* w3p  = (ushort*)(ws + 114688);
    float*  bq   = (float*)(ws + 118784);
    float*  al1  = (float*)(ws + 119040);
    float*  bt1  = (float*)(ws + 119552);
    float*  al2  = (float*)(ws + 120064);
    float*  bt2  = (float*)(ws + 120320);
    float*  al3  = (float*)(ws + 120576);
    float*  bt3  = (float*)(ws + 120704);
    float*  qhb  = (float*)(ws + 131072);              // 2 MB
    ushort* ce   = (ushort*)(ws + 131072 + 2097152);   // 1 MB
    ushort* ifav = (ushort*)(ws + 131072 + 3145728);   // 4 MB

    k_prep<<<201, 256, 0, stream>>>(Wi, bi, Wk, Wq, W1, W2, W3,
                                    b1, g1, be1, m1, v1,
                                    b2, g2, be2, m2, v2,
                                    b3, g3, be3, m3, v3,
                                    wikp, wiqp, bq, wip, w1p, w2p, w3p,
                                    al1, bt1, al2, bt2, al3, bt3);
    k_embed<<<Bn / 64, 256, 0, stream>>>(cand, wip, wiqp, bi, bq, ce, qhb);
    k_main<<<Bn, 256, 0, stream>>>(hist, hlen, qhb, Wv, wikp, ifav);
    k_mlp<<<Bn / 64, 256, 0, stream>>>(ifav, ce, bi, wip, w1p, w2p, w3p,
                                       al1, bt1, al2, bt2, al3, bt3, Wo, bo, out);
}